// Round 12
// baseline (354.624 us; speedup 1.0000x reference)
//
#include <hip/hip_runtime.h>
#include <hip/hip_bf16.h>

typedef __attribute__((ext_vector_type(8))) short short8v;
typedef __attribute__((ext_vector_type(4))) float float4v;
typedef __attribute__((ext_vector_type(2))) float f32x2;

__device__ __forceinline__ unsigned short f2bf(float f) {
    unsigned u = __float_as_uint(f);
    u += 0x7FFFu + ((u >> 16) & 1u);           // RNE
    return (unsigned short)(u >> 16);
}
__device__ __forceinline__ float bflo(unsigned u) { return __uint_as_float(u << 16); }
__device__ __forceinline__ float bfhi(unsigned u) { return __uint_as_float(u & 0xFFFF0000u); }
__device__ __forceinline__ float lrelu02(float a) { return (a > 0.f) ? a : 0.2f * a; }
__device__ __forceinline__ unsigned pack2(float a, float b) {
    return (unsigned)f2bf(a) | ((unsigned)f2bf(b) << 16);
}

// 8 fp8 values of one uint word pair -> 4 accs, weighted
#define W8F(word, C, A0, A1, A2, A3)                                    \
    { f32x2 lo_ = __builtin_amdgcn_cvt_pk_f32_fp8((word), 0);           \
      f32x2 hi_ = __builtin_amdgcn_cvt_pk_f32_fp8((word), 1);           \
      A0 += lo_[0] * (C); A1 += lo_[1] * (C);                           \
      A2 += hi_[0] * (C); A3 += hi_[1] * (C); }
#define W8S(word, A0, A1, A2, A3)                                       \
    { f32x2 lo_ = __builtin_amdgcn_cvt_pk_f32_fp8((word), 0);           \
      f32x2 hi_ = __builtin_amdgcn_cvt_pk_f32_fp8((word), 1);           \
      A0 += lo_[0]; A1 += lo_[1]; A2 += hi_[0]; A3 += hi_[1]; }

// ---------------- setup: weight transpose+bf16 convert, zero deg/sums/cnts ----------------
__global__ void setup_kernel(const float* __restrict__ W1, const float* __restrict__ W2,
                             const float* __restrict__ W3, const float* __restrict__ WG,
                             unsigned short* __restrict__ Wt1, unsigned short* __restrict__ Wt2,
                             unsigned short* __restrict__ Wt3, unsigned short* __restrict__ WtG,
                             int* __restrict__ deg, float* __restrict__ sums,
                             float* __restrict__ cnts, int N, int G) {
    int idx = blockIdx.x * blockDim.x + threadIdx.x;
    if (idx < 16384) {
        int i = idx;           int k = i >> 7, n = i & 127;  Wt1[n * 128 + k] = f2bf(W1[i]);
    } else if (idx < 32768) {
        int i = idx - 16384;   int k = i >> 7, n = i & 127;  Wt2[n * 128 + k] = f2bf(W2[i]);
    } else if (idx < 49152) {
        int i = idx - 32768;   int k = i >> 7, n = i & 127;  Wt3[n * 128 + k] = f2bf(W3[i]);
    } else if (idx < 81920) {
        int i = idx - 49152;   int k = i >> 8, n = i & 255;  WtG[n * 128 + k] = f2bf(WG[i]);
    } else if (idx < 81920 + N) {
        deg[idx - 81920] = 0;
    } else if (idx < 81920 + N + G * 128) {
        sums[idx - 81920 - N] = 0.f;
    } else if (idx < 81920 + N + G * 128 + G) {
        cnts[idx - 81920 - N - G * 128] = 0.f;
    }
}

// ---------------- CSR build ----------------

__global__ void deg_kernel(const int* __restrict__ dst, int* __restrict__ deg, int E) {
    int i = blockIdx.x * blockDim.x + threadIdx.x;
    if (i < E) atomicAdd(&deg[dst[i]], 1);
}

__global__ __launch_bounds__(1024) void scan1_kernel(const int* __restrict__ deg,
                                                     int* __restrict__ ptr,
                                                     float* __restrict__ dinv,
                                                     int* __restrict__ bsum, int N) {
    __shared__ int wsum[16];
    const int tid = threadIdx.x, wid = tid >> 6, lane = tid & 63;
    int i = blockIdx.x * 1024 + tid;
    int v = (i < N) ? deg[i] : 0;
    int x = v;
#pragma unroll
    for (int o = 1; o < 64; o <<= 1) {
        int t = __shfl_up(x, o);
        if (lane >= o) x += t;
    }
    if (lane == 63) wsum[wid] = x;
    __syncthreads();
    if (wid == 0 && lane < 16) {
        int w = wsum[lane];
#pragma unroll
        for (int o = 1; o < 16; o <<= 1) {
            int t = __shfl_up(w, o);
            if (lane >= o) w += t;
        }
        wsum[lane] = w;
    }
    __syncthreads();
    int excl = (wid ? wsum[wid - 1] : 0) + x - v;
    if (i < N) {
        ptr[i] = excl;
        dinv[i] = rsqrtf((float)v + 1.0f);
    }
    if (tid == 0) bsum[blockIdx.x] = wsum[15];
}

__global__ __launch_bounds__(1024) void scan2_kernel(int* __restrict__ ptr,
                                                     int* __restrict__ cursor,
                                                     const int* __restrict__ bsum,
                                                     int N, int nb) {
    __shared__ int offs;
    const int tid = threadIdx.x;
    if (tid < 64) {
        int s = 0;
        for (int j = (int)tid; j < (int)blockIdx.x; j += 64) s += bsum[j];
#pragma unroll
        for (int o = 1; o < 64; o <<= 1) s += __shfl_xor(s, o);
        if (tid == 0) offs = s;
    }
    __syncthreads();
    int off = offs;
    int i = blockIdx.x * 1024 + tid;
    if (i < N) {
        int v = ptr[i] + off;
        ptr[i] = v;
        cursor[i] = v;
    }
    if ((int)blockIdx.x == nb - 1 && tid == 0) ptr[N] = off + bsum[nb - 1];
}

__global__ void csr_fill_kernel(const int* __restrict__ src, const int* __restrict__ dst,
                                int* __restrict__ cursor, int* __restrict__ csr_src, int E) {
    int e = blockIdx.x * blockDim.x + threadIdx.x;
    if (e < E) {
        int pos = atomicAdd(&cursor[dst[e]], 1);
        csr_src[pos] = src[e];
    }
}

// ---------------- MFMA linear, fp8 permuted out: Yf8 = fp8(dinv[n]*(X@W)) ----------------
template<bool XF32>
__global__ __launch_bounds__(256) void lin_mfma_f8_kernel(const void* __restrict__ Xv,
                                                          const unsigned short* __restrict__ Wt,
                                                          const float* __restrict__ dinv,
                                                          uint2* __restrict__ Yf8, int N) {
    constexpr int NF = 8;
    int wave = threadIdx.x >> 6;
    int lane = threadIdx.x & 63;
    int lr = lane & 15;
    int hk = lane >> 4;
    int rowbase = blockIdx.x * 64 + wave * 16;
    int arow = rowbase + lr; if (arow > N - 1) arow = N - 1;
    float4v acc[NF];
#pragma unroll
    for (int i = 0; i < NF; ++i) acc[i] = (float4v){0.f, 0.f, 0.f, 0.f};
#pragma unroll
    for (int ks = 0; ks < 4; ++ks) {
        int k0 = ks * 32 + hk * 8;
        short8v a;
        if (XF32) {
            const float* xp = (const float*)Xv + (size_t)arow * 128 + k0;
            float4 a0 = *(const float4*)xp;
            float4 a1 = *(const float4*)(xp + 4);
            a[0] = (short)f2bf(a0.x); a[1] = (short)f2bf(a0.y);
            a[2] = (short)f2bf(a0.z); a[3] = (short)f2bf(a0.w);
            a[4] = (short)f2bf(a1.x); a[5] = (short)f2bf(a1.y);
            a[6] = (short)f2bf(a1.z); a[7] = (short)f2bf(a1.w);
        } else {
            a = *(const short8v*)((const unsigned short*)Xv + (size_t)arow * 128 + k0);
        }
#pragma unroll
        for (int nf = 0; nf < NF; ++nf) {
            short8v b = *(const short8v*)(Wt + (size_t)(nf * 16 + lr) * 128 + k0);
            acc[nf] = __builtin_amdgcn_mfma_f32_16x16x32_bf16(a, b, acc[nf], 0, 0, 0);
        }
    }
#pragma unroll
    for (int r = 0; r < 4; ++r) {
        int orow = rowbase + hk * 4 + r;
        if (orow < N) {
            float s = dinv[orow];
            int w0 = __builtin_amdgcn_cvt_pk_fp8_f32(acc[0][r] * s, acc[1][r] * s, 0, 0);
            w0 = __builtin_amdgcn_cvt_pk_fp8_f32(acc[2][r] * s, acc[3][r] * s, w0, 1);
            int w1 = __builtin_amdgcn_cvt_pk_fp8_f32(acc[4][r] * s, acc[5][r] * s, 0, 0);
            w1 = __builtin_amdgcn_cvt_pk_fp8_f32(acc[6][r] * s, acc[7][r] * s, w1, 1);
            Yf8[(size_t)orow * 16 + lr] = make_uint2((unsigned)w0, (unsigned)w1);
        }
    }
}

// ---------------- GAT linear (KO=256) + fused attention logits; fp8 permuted output ----------------
__global__ __launch_bounds__(256) void lin_mfma_attn_kernel(const unsigned short* __restrict__ X,
                                                            const unsigned short* __restrict__ Wt,
                                                            const float* __restrict__ attS,
                                                            const float* __restrict__ attD,
                                                            uint2* __restrict__ Yf8,
                                                            float2* __restrict__ al_s2,
                                                            float2* __restrict__ al_d2, int N) {
    constexpr int NF = 16;
    int wave = threadIdx.x >> 6;
    int lane = threadIdx.x & 63;
    int lr = lane & 15;
    int hk = lane >> 4;
    int rowbase = blockIdx.x * 64 + wave * 16;
    int arow = rowbase + lr; if (arow > N - 1) arow = N - 1;
    float4v acc[NF];
#pragma unroll
    for (int i = 0; i < NF; ++i) acc[i] = (float4v){0.f, 0.f, 0.f, 0.f};
#pragma unroll
    for (int ks = 0; ks < 4; ++ks) {
        int k0 = ks * 32 + hk * 8;
        short8v a = *(const short8v*)(X + (size_t)arow * 128 + k0);
#pragma unroll
        for (int nf = 0; nf < NF; ++nf) {
            short8v b = *(const short8v*)(Wt + (size_t)(nf * 16 + lr) * 128 + k0);
            acc[nf] = __builtin_amdgcn_mfma_f32_16x16x32_bf16(a, b, acc[nf], 0, 0, 0);
        }
    }
    float as0[8], as1[8], ad0[8], ad1[8];
#pragma unroll
    for (int q = 0; q < 8; ++q) {
        as0[q] = attS[q * 16 + lr];
        as1[q] = attS[128 + q * 16 + lr];
        ad0[q] = attD[q * 16 + lr];
        ad1[q] = attD[128 + q * 16 + lr];
    }
#pragma unroll
    for (int r = 0; r < 4; ++r) {
        int orow = rowbase + hk * 4 + r;
        float s0 = 0.f, s1 = 0.f, d0 = 0.f, d1 = 0.f;
#pragma unroll
        for (int q = 0; q < 8; ++q) {
            s0 += acc[q][r] * as0[q];
            d0 += acc[q][r] * ad0[q];
            s1 += acc[q + 8][r] * as1[q];
            d1 += acc[q + 8][r] * ad1[q];
        }
#pragma unroll
        for (int o = 1; o < 16; o <<= 1) {
            s0 += __shfl_xor(s0, o);
            s1 += __shfl_xor(s1, o);
            d0 += __shfl_xor(d0, o);
            d1 += __shfl_xor(d1, o);
        }
        if (orow < N) {
            int w0 = __builtin_amdgcn_cvt_pk_fp8_f32(acc[0][r], acc[1][r], 0, 0);
            w0 = __builtin_amdgcn_cvt_pk_fp8_f32(acc[2][r], acc[3][r], w0, 1);
            int w1 = __builtin_amdgcn_cvt_pk_fp8_f32(acc[4][r], acc[5][r], 0, 0);
            w1 = __builtin_amdgcn_cvt_pk_fp8_f32(acc[6][r], acc[7][r], w1, 1);
            Yf8[(size_t)orow * 32 + lr] = make_uint2((unsigned)w0, (unsigned)w1);
            int w2 = __builtin_amdgcn_cvt_pk_fp8_f32(acc[8][r], acc[9][r], 0, 0);
            w2 = __builtin_amdgcn_cvt_pk_fp8_f32(acc[10][r], acc[11][r], w2, 1);
            int w3 = __builtin_amdgcn_cvt_pk_fp8_f32(acc[12][r], acc[13][r], 0, 0);
            w3 = __builtin_amdgcn_cvt_pk_fp8_f32(acc[14][r], acc[15][r], w3, 1);
            Yf8[(size_t)orow * 32 + 16 + lr] = make_uint2((unsigned)w2, (unsigned)w3);
            if (lr == 0) {
                al_s2[orow] = make_float2(s0, s1);
                al_d2[orow] = make_float2(d0, d1);
            }
        }
    }
}

// ---------------- GCN gather (fp8 rows 128B): 8 lanes/row uint4, 8 edges in flight ----------------
__global__ __launch_bounds__(256) void gcn_gather_kernel(const uint4* __restrict__ y,
                                                         const float* __restrict__ dinv,
                                                         const int* __restrict__ ptr,
                                                         const int* __restrict__ csr,
                                                         const float* __restrict__ bias,
                                                         uint4* __restrict__ out, int N) {
    __shared__ int stg[4][64];
    __shared__ float vals[4][128];
    int w = threadIdx.x >> 6;
    int node = blockIdx.x * 4 + w;
    if (node >= N) return;
    int lane = threadIdx.x & 63;
    int q = lane & 7;
    int g = lane >> 3;                 // 8 edge-parity groups
    float a0 = 0, a1 = 0, a2 = 0, a3 = 0, a4 = 0, a5 = 0, a6 = 0, a7 = 0;
    float a8 = 0, a9 = 0, a10 = 0, a11 = 0, a12 = 0, a13 = 0, a14 = 0, a15 = 0;
    int b0 = ptr[node], b1 = ptr[node + 1];
    for (int p0 = b0; p0 < b1; p0 += 64) {
        int m = b1 - p0; if (m > 64) m = 64;
        if (lane < m) stg[w][lane] = __builtin_nontemporal_load(csr + p0 + lane);
        int j = g;
        for (; j + 8 < m; j += 16) {
            int s0 = stg[w][j], s1 = stg[w][j + 8];
            uint4 u0 = y[(size_t)s0 * 8 + q];
            uint4 u1 = y[(size_t)s1 * 8 + q];
            W8S(u0.x, a0, a1, a2, a3)   W8S(u0.y, a4, a5, a6, a7)
            W8S(u0.z, a8, a9, a10, a11) W8S(u0.w, a12, a13, a14, a15)
            W8S(u1.x, a0, a1, a2, a3)   W8S(u1.y, a4, a5, a6, a7)
            W8S(u1.z, a8, a9, a10, a11) W8S(u1.w, a12, a13, a14, a15)
        }
        if (j < m) {
            int s0 = stg[w][j];
            uint4 u0 = y[(size_t)s0 * 8 + q];
            W8S(u0.x, a0, a1, a2, a3)   W8S(u0.y, a4, a5, a6, a7)
            W8S(u0.z, a8, a9, a10, a11) W8S(u0.w, a12, a13, a14, a15)
        }
    }
#pragma unroll
    for (int o = 8; o < 64; o <<= 1) {
        a0 += __shfl_xor(a0, o);  a1 += __shfl_xor(a1, o);
        a2 += __shfl_xor(a2, o);  a3 += __shfl_xor(a3, o);
        a4 += __shfl_xor(a4, o);  a5 += __shfl_xor(a5, o);
        a6 += __shfl_xor(a6, o);  a7 += __shfl_xor(a7, o);
        a8 += __shfl_xor(a8, o);  a9 += __shfl_xor(a9, o);
        a10 += __shfl_xor(a10, o); a11 += __shfl_xor(a11, o);
        a12 += __shfl_xor(a12, o); a13 += __shfl_xor(a13, o);
        a14 += __shfl_xor(a14, o); a15 += __shfl_xor(a15, o);
    }
    // self loop
    {
        uint4 u = y[(size_t)node * 8 + q];
        W8S(u.x, a0, a1, a2, a3)   W8S(u.y, a4, a5, a6, a7)
        W8S(u.z, a8, a9, a10, a11) W8S(u.w, a12, a13, a14, a15)
    }
    // un-permute: lane q<8 holds bytes q*16+i; store vals[b], read b=(c&15)*8+(c>>4)
    if (lane < 8) {
        float dn = dinv[node];
        vals[w][q * 16 + 0] = a0 * dn;  vals[w][q * 16 + 1] = a1 * dn;
        vals[w][q * 16 + 2] = a2 * dn;  vals[w][q * 16 + 3] = a3 * dn;
        vals[w][q * 16 + 4] = a4 * dn;  vals[w][q * 16 + 5] = a5 * dn;
        vals[w][q * 16 + 6] = a6 * dn;  vals[w][q * 16 + 7] = a7 * dn;
        vals[w][q * 16 + 8] = a8 * dn;  vals[w][q * 16 + 9] = a9 * dn;
        vals[w][q * 16 + 10] = a10 * dn; vals[w][q * 16 + 11] = a11 * dn;
        vals[w][q * 16 + 12] = a12 * dn; vals[w][q * 16 + 13] = a13 * dn;
        vals[w][q * 16 + 14] = a14 * dn; vals[w][q * 16 + 15] = a15 * dn;
    }
    if (lane < 16) {
        float o[8];
#pragma unroll
        for (int i = 0; i < 8; ++i) {
            int c = lane * 8 + i;
            int p = (c & 15) * 8 + (c >> 4);
            o[i] = fmaxf(vals[w][p] + bias[c], 0.f);
        }
        out[(size_t)node * 16 + lane] = make_uint4(pack2(o[0], o[1]), pack2(o[2], o[3]),
                                                   pack2(o[4], o[5]), pack2(o[6], o[7]));
    }
}

// ---------------- GAT gather (fp8 rows 256B): 16 lanes/row uint4, 4 edges in flight ----------------
__global__ __launch_bounds__(256) void gat_gather_kernel(const uint4* __restrict__ h2,
                                                         const float2* __restrict__ al_s2,
                                                         const float2* __restrict__ al_d2,
                                                         const int* __restrict__ ptr,
                                                         const int* __restrict__ csr,
                                                         const float* __restrict__ bias,
                                                         uint4* __restrict__ out, int N) {
    __shared__ uint4 stg[4][64];
    __shared__ float vals[4][128];
    int w = threadIdx.x >> 6;
    int node = blockIdx.x * 4 + w;
    if (node >= N) return;
    int lane = threadIdx.x & 63;
    int q = lane & 15;                 // uint4 index within 256B row
    int head = q >> 3;
    int g = lane >> 4;                 // 4 edge-parity groups
    int b0 = ptr[node], b1 = ptr[node + 1];
    float2 ad = al_d2[node];

    float den0 = 0.f, den1 = 0.f;
    float a0 = 0, a1 = 0, a2 = 0, a3 = 0, a4 = 0, a5 = 0, a6 = 0, a7 = 0;
    float a8 = 0, a9 = 0, a10 = 0, a11 = 0, a12 = 0, a13 = 0, a14 = 0, a15 = 0;

    for (int p0 = b0; p0 < b1; p0 += 64) {
        int m = b1 - p0; if (m > 64) m = 64;
        int idx = (lane < m) ? __builtin_nontemporal_load(csr + p0 + lane) : 0;
        float2 als = al_s2[idx];
        float e0 = __expf(lrelu02(als.x + ad.x));
        float e1 = __expf(lrelu02(als.y + ad.y));
        if (lane >= m) { e0 = 0.f; e1 = 0.f; }
        den0 += e0; den1 += e1;
        stg[w][lane] = make_uint4((unsigned)idx, __float_as_uint(e0), __float_as_uint(e1), 0u);
        int j = g;
        for (; j + 4 < m; j += 8) {
            uint4 t0 = stg[w][j], t1 = stg[w][j + 4];
            uint4 u0 = h2[(size_t)t0.x * 16 + q];
            uint4 u1 = h2[(size_t)t1.x * 16 + q];
            float c0 = __uint_as_float(head ? t0.z : t0.y);
            float c1 = __uint_as_float(head ? t1.z : t1.y);
            W8F(u0.x, c0, a0, a1, a2, a3)   W8F(u0.y, c0, a4, a5, a6, a7)
            W8F(u0.z, c0, a8, a9, a10, a11) W8F(u0.w, c0, a12, a13, a14, a15)
            W8F(u1.x, c1, a0, a1, a2, a3)   W8F(u1.y, c1, a4, a5, a6, a7)
            W8F(u1.z, c1, a8, a9, a10, a11) W8F(u1.w, c1, a12, a13, a14, a15)
        }
        if (j < m) {
            uint4 t0 = stg[w][j];
            uint4 u0 = h2[(size_t)t0.x * 16 + q];
            float c0 = __uint_as_float(head ? t0.z : t0.y);
            W8F(u0.x, c0, a0, a1, a2, a3)   W8F(u0.y, c0, a4, a5, a6, a7)
            W8F(u0.z, c0, a8, a9, a10, a11) W8F(u0.w, c0, a12, a13, a14, a15)
        }
    }
    // combine 4 parity groups
#pragma unroll
    for (int o = 16; o < 64; o <<= 1) {
        a0 += __shfl_xor(a0, o);  a1 += __shfl_xor(a1, o);
        a2 += __shfl_xor(a2, o);  a3 += __shfl_xor(a3, o);
        a4 += __shfl_xor(a4, o);  a5 += __shfl_xor(a5, o);
        a6 += __shfl_xor(a6, o);  a7 += __shfl_xor(a7, o);
        a8 += __shfl_xor(a8, o);  a9 += __shfl_xor(a9, o);
        a10 += __shfl_xor(a10, o); a11 += __shfl_xor(a11, o);
        a12 += __shfl_xor(a12, o); a13 += __shfl_xor(a13, o);
        a14 += __shfl_xor(a14, o); a15 += __shfl_xor(a15, o);
    }
#pragma unroll
    for (int o = 1; o < 64; o <<= 1) {
        den0 += __shfl_xor(den0, o);
        den1 += __shfl_xor(den1, o);
    }
    // self loop
    {
        float2 as_ = al_s2[node];
        float e0s = __expf(lrelu02(as_.x + ad.x));
        float e1s = __expf(lrelu02(as_.y + ad.y));
        den0 += e0s; den1 += e1s;
        float ea = head ? e1s : e0s;
        uint4 u = h2[(size_t)node * 16 + q];
        W8F(u.x, ea, a0, a1, a2, a3)   W8F(u.y, ea, a4, a5, a6, a7)
        W8F(u.z, ea, a8, a9, a10, a11) W8F(u.w, ea, a12, a13, a14, a15)
    }
    float inv = 1.f / ((head ? den1 : den0) + 1e-16f);
    a0 *= inv; a1 *= inv; a2 *= inv; a3 *= inv;
    a4 *= inv; a5 *= inv; a6 *= inv; a7 *= inv;
    a8 *= inv; a9 *= inv; a10 *= inv; a11 *= inv;
    a12 *= inv; a13 *= inv; a14 *= inv; a15 *= inv;
    // mean over heads: partner lane q^8 holds the other head, same in-head bytes
    a0 += __shfl_xor(a0, 8);  a1 += __shfl_xor(a1, 8);
    a2 += __shfl_xor(a2, 8);  a3 += __shfl_xor(a3, 8);
    a4 += __shfl_xor(a4, 8);  a5 += __shfl_xor(a5, 8);
    a6 += __shfl_xor(a6, 8);  a7 += __shfl_xor(a7, 8);
    a8 += __shfl_xor(a8, 8);  a9 += __shfl_xor(a9, 8);
    a10 += __shfl_xor(a10, 8); a11 += __shfl_xor(a11, 8);
    a12 += __shfl_xor(a12, 8); a13 += __shfl_xor(a13, 8);
    a14 += __shfl_xor(a14, 8); a15 += __shfl_xor(a15, 8);
    // un-permute: lane q<8 holds in-head bytes q*16+i; read b=(c&15)*8+(c>>4)
    if (lane < 8) {
        vals[w][q * 16 + 0] = a0;  vals[w][q * 16 + 1] = a1;
        vals[w][q * 16 + 2] = a2;  vals[w][q * 16 + 3] = a3;
        vals[w][q * 16 + 4] = a4;  vals[w][q * 16 + 5] = a5;
        vals[w][q * 16 + 6] = a6;  vals[w][q * 16 + 7] = a7;
        vals[w][q * 16 + 8] = a8;  vals[w][q * 16 + 9] = a9;
        vals[w][q * 16 + 10] = a10; vals[w][q * 16 + 11] = a11;
        vals[w][q * 16 + 12] = a12; vals[w][q * 16 + 13] = a13;
        vals[w][q * 16 + 14] = a14; vals[w][q * 16 + 15] = a15;
    }
    if (lane < 16) {
        float o[8];
#pragma unroll
        for (int i = 0; i < 8; ++i) {
            int c = lane * 8 + i;
            int p = (c & 15) * 8 + (c >> 4);
            o[i] = fmaxf(0.5f * vals[w][p] + bias[c], 0.f);
        }
        out[(size_t)node * 16 + lane] = make_uint4(pack2(o[0], o[1]), pack2(o[2], o[3]),
                                                   pack2(o[4], o[5]), pack2(o[6], o[7]));
    }
}

// ---------------- pooling (bf16 input, sorted batch): one 32-node chunk per wave ----------------
__global__ __launch_bounds__(256) void pool_kernel(const unsigned* __restrict__ h,
                                                   const int* __restrict__ batch,
                                                   float* __restrict__ sums,
                                                   float* __restrict__ counts, int N) {
    const int PER = 32;
    int wave = threadIdx.x >> 6;
    int f = threadIdx.x & 63;
    int n0 = (blockIdx.x * 4 + wave) * PER;
    int n1 = min(N, n0 + PER);
    if (n0 >= n1) return;
    int cur = -1;
    float a0 = 0.f, a1 = 0.f, cnt = 0.f;
    for (int n = n0; n < n1; ++n) {
        int g = batch[n];
        if (g != cur) {
            if (cur >= 0) {
                atomicAdd(&sums[cur * 128 + f * 2], a0);
                atomicAdd(&sums[cur * 128 + f * 2 + 1], a1);
                if (f == 0) atomicAdd(&counts[cur], cnt);
            }
            cur = g; a0 = a1 = cnt = 0.f;
        }
        unsigned u = h[(size_t)n * 64 + f];
        a0 += bflo(u); a1 += bfhi(u); cnt += 1.f;
    }
    if (cur >= 0) {
        atomicAdd(&sums[cur * 128 + f * 2], a0);
        atomicAdd(&sums[cur * 128 + f * 2 + 1], a1);
        if (f == 0) atomicAdd(&counts[cur], cnt);
    }
}

// ---------------- MLP head + log_softmax: one block per graph ----------------
__global__ __launch_bounds__(128) void head_kernel(const float* __restrict__ sums,
                                                   const float* __restrict__ counts,
                                                   const float* __restrict__ fc1W,
                                                   const float* __restrict__ fc1b,
                                                   const float* __restrict__ fc2W,
                                                   const float* __restrict__ fc2b,
                                                   float* __restrict__ out) {
    int g = blockIdx.x;
    int tid = threadIdx.x;
    __shared__ float gm[128];
    __shared__ float h1[128];
    __shared__ float part[4][32];
    float s = sums[g * 128 + tid];
    gm[tid] = s / fmaxf(counts[g], 1.f) + s;
    __syncthreads();
    float acc = fc1b[tid];
    for (int k = 0; k < 128; ++k) acc += gm[k] * fc1W[k * 128 + tid];
    h1[tid] = fmaxf(acc, 0.f);
    __syncthreads();
    int c = tid & 31, p = tid >> 5;
    float a2 = 0.f;
    for (int k = p * 32; k < p * 32 + 32; ++k) a2 += h1[k] * fc2W[k * 32 + c];
    part[p][c] = a2;
    __syncthreads();
    if (tid < 32) {
        float v = part[0][tid] + part[1][tid] + part[2][tid] + part[3][tid] + fc2b[tid];
        float m = v;
#pragma unroll
        for (int o = 1; o < 32; o <<= 1) m = fmaxf(m, __shfl_xor(m, o));
        float e = __expf(v - m);
        float ssum = e;
#pragma unroll
        for (int o = 1; o < 32; o <<= 1) ssum += __shfl_xor(ssum, o);
        out[g * 32 + tid] = v - m - logf(ssum);
    }
}

// ---------------- launch ----------------

extern "C" void kernel_launch(void* const* d_in, const int* in_sizes, int n_in,
                              void* d_out, int out_size, void* d_ws, size_t ws_size,
                              hipStream_t stream) {
    const float* x     = (const float*)d_in[0];
    const int*   eidx  = (const int*)d_in[1];
    const int*   batch = (const int*)d_in[2];
    const float* W1 = (const float*)d_in[3];
    const float* b1 = (const float*)d_in[4];
    const float* W2 = (const float*)d_in[5];
    const float* b2 = (const float*)d_in[6];
    const float* W3 = (const float*)d_in[7];
    const float* b3 = (const float*)d_in[8];
    const float* gatW   = (const float*)d_in[9];
    const float* attSrc = (const float*)d_in[10];
    const float* attDst = (const float*)d_in[11];
    const float* gatB   = (const float*)d_in[12];
    const float* fc1W = (const float*)d_in[13];
    const float* fc1b = (const float*)d_in[14];
    const float* fc2W = (const float*)d_in[15];
    const float* fc2b = (const float*)d_in[16];
    float* out = (float*)d_out;

    const int N  = in_sizes[0] / 128;
    const int E  = in_sizes[1] / 2;
    const int OUT = in_sizes[15] / 128;
    const int G   = out_size / OUT;

    const int* src = eidx;
    const int* dst = eidx + E;

    // workspace carve-up
    char* ws = (char*)d_ws;
    size_t off = 0;
    auto carve = [&](size_t bytes) { char* p = ws + off; off += (bytes + 255) & ~255ull; return p; };
    uint2*          yf8  = (uint2*)carve((size_t)N * 128);
    unsigned short* hb   = (unsigned short*)carve((size_t)N * 128 * 2);
    uint2*          gb8  = (uint2*)carve((size_t)N * 256);
    unsigned short* ob   = (unsigned short*)carve((size_t)N * 128 * 2);
    unsigned short* Wt1 = (unsigned short*)carve(128 * 128 * 2);
    unsigned short* Wt2 = (unsigned short*)carve(128 * 128 * 2);
    unsigned short* Wt3 = (unsigned short*)carve(128 * 128 * 2);
    unsigned short* WtG = (unsigned short*)carve(256 * 128 * 2);
    int*   deg   = (int*)carve((size_t)N * 4);
    float* dinv  = (float*)carve((size_t)N * 4);
    int*   ptr   = (int*)carve((size_t)(N + 1) * 4);
    int*   cursor= (int*)carve((size_t)N * 4);
    int*   csrS  = (int*)carve((size_t)E * 4);
    int*   bsum  = (int*)carve(256 * 4);
    float* al_s  = (float*)carve((size_t)N * 2 * 4);
    float* al_d  = (float*)carve((size_t)N * 2 * 4);
    float* sums  = (float*)carve((size_t)G * 128 * 4);
    float* cnts  = (float*)carve((size_t)G * 4);

    const int B = 256;
    dim3 blk(B);
    auto cdiv = [](long long a, long long b) { return (int)((a + b - 1) / b); };
    const int nb = cdiv(N, 1024);

    // setup: weight conversions + zero deg/sums/cnts (single launch)
    setup_kernel<<<cdiv(81920 + N + G * 128 + G, B), blk, 0, stream>>>(
        W1, W2, W3, gatW, Wt1, Wt2, Wt3, WtG, deg, sums, cnts, N, G);

    // CSR build over dst (parallel two-phase scan)
    deg_kernel<<<cdiv(E, B), blk, 0, stream>>>(dst, deg, E);
    scan1_kernel<<<nb, 1024, 0, stream>>>(deg, ptr, dinv, bsum, N);
    scan2_kernel<<<nb, 1024, 0, stream>>>(ptr, cursor, bsum, N, nb);
    csr_fill_kernel<<<cdiv(E, B), blk, 0, stream>>>(src, dst, cursor, csrS, E);

    // GCN layers (fp8 lin outputs pre-scaled by dinv, bf16 gather outputs)
    lin_mfma_f8_kernel<true><<<cdiv(N, 64), blk, 0, stream>>>(x, Wt1, dinv, yf8, N);
    gcn_gather_kernel<<<cdiv(N, 4), blk, 0, stream>>>((const uint4*)yf8, dinv, ptr, csrS, b1, (uint4*)hb, N);
    lin_mfma_f8_kernel<false><<<cdiv(N, 64), blk, 0, stream>>>(hb, Wt2, dinv, yf8, N);
    gcn_gather_kernel<<<cdiv(N, 4), blk, 0, stream>>>((const uint4*)yf8, dinv, ptr, csrS, b2, (uint4*)hb, N);
    lin_mfma_f8_kernel<false><<<cdiv(N, 64), blk, 0, stream>>>(hb, Wt3, dinv, yf8, N);
    gcn_gather_kernel<<<cdiv(N, 4), blk, 0, stream>>>((const uint4*)yf8, dinv, ptr, csrS, b3, (uint4*)hb, N);

    // GAT: GEMM + fused attention logits (fp8 out), then gather
    lin_mfma_attn_kernel<<<cdiv(N, 64), blk, 0, stream>>>(hb, WtG, attSrc, attDst, gb8,
                                                          (float2*)al_s, (float2*)al_d, N);
    gat_gather_kernel<<<cdiv(N, 4), blk, 0, stream>>>((const uint4*)gb8, (const float2*)al_s, (const float2*)al_d,
                                                      ptr, csrS, gatB, (uint4*)ob, N);

    // pooling
    pool_kernel<<<cdiv(N, 128), blk, 0, stream>>>((const unsigned*)ob, batch, sums, cnts, N);

    // head: one block per graph
    head_kernel<<<G, dim3(128), 0, stream>>>(sums, cnts, fc1W, fc1b, fc2W, fc2b, out);
}

// Round 13
// 317.549 us; speedup vs baseline: 1.1168x; 1.1168x over previous
//
#include <hip/hip_runtime.h>
#include <hip/hip_bf16.h>

typedef __attribute__((ext_vector_type(8))) short short8v;
typedef __attribute__((ext_vector_type(4))) float float4v;
typedef __attribute__((ext_vector_type(2))) float f32x2;

__device__ __forceinline__ unsigned short f2bf(float f) {
    unsigned u = __float_as_uint(f);
    u += 0x7FFFu + ((u >> 16) & 1u);           // RNE
    return (unsigned short)(u >> 16);
}
__device__ __forceinline__ float bflo(unsigned u) { return __uint_as_float(u << 16); }
__device__ __forceinline__ float bfhi(unsigned u) { return __uint_as_float(u & 0xFFFF0000u); }
__device__ __forceinline__ float lrelu02(float a) { return (a > 0.f) ? a : 0.2f * a; }
__device__ __forceinline__ unsigned pack2(float a, float b) {
    return (unsigned)f2bf(a) | ((unsigned)f2bf(b) << 16);
}

// ---------------- setup: weight transpose+bf16 convert, zero deg/sums/cnts ----------------
__global__ void setup_kernel(const float* __restrict__ W1, const float* __restrict__ W2,
                             const float* __restrict__ W3, const float* __restrict__ WG,
                             unsigned short* __restrict__ Wt1, unsigned short* __restrict__ Wt2,
                             unsigned short* __restrict__ Wt3, unsigned short* __restrict__ WtG,
                             int* __restrict__ deg, float* __restrict__ sums,
                             float* __restrict__ cnts, int N, int G) {
    int idx = blockIdx.x * blockDim.x + threadIdx.x;
    if (idx < 16384) {
        int i = idx;           int k = i >> 7, n = i & 127;  Wt1[n * 128 + k] = f2bf(W1[i]);
    } else if (idx < 32768) {
        int i = idx - 16384;   int k = i >> 7, n = i & 127;  Wt2[n * 128 + k] = f2bf(W2[i]);
    } else if (idx < 49152) {
        int i = idx - 32768;   int k = i >> 7, n = i & 127;  Wt3[n * 128 + k] = f2bf(W3[i]);
    } else if (idx < 81920) {
        int i = idx - 49152;   int k = i >> 8, n = i & 255;  WtG[n * 128 + k] = f2bf(WG[i]);
    } else if (idx < 81920 + N) {
        deg[idx - 81920] = 0;
    } else if (idx < 81920 + N + G * 128) {
        sums[idx - 81920 - N] = 0.f;
    } else if (idx < 81920 + N + G * 128 + G) {
        cnts[idx - 81920 - N - G * 128] = 0.f;
    }
}

// ---------------- CSR build ----------------

__global__ void deg_kernel(const int* __restrict__ dst, int* __restrict__ deg, int E) {
    int i = blockIdx.x * blockDim.x + threadIdx.x;
    if (i < E) atomicAdd(&deg[dst[i]], 1);
}

__global__ __launch_bounds__(1024) void scan1_kernel(const int* __restrict__ deg,
                                                     int* __restrict__ ptr,
                                                     float* __restrict__ dinv,
                                                     int* __restrict__ bsum, int N) {
    __shared__ int wsum[16];
    const int tid = threadIdx.x, wid = tid >> 6, lane = tid & 63;
    int i = blockIdx.x * 1024 + tid;
    int v = (i < N) ? deg[i] : 0;
    int x = v;
#pragma unroll
    for (int o = 1; o < 64; o <<= 1) {
        int t = __shfl_up(x, o);
        if (lane >= o) x += t;
    }
    if (lane == 63) wsum[wid] = x;
    __syncthreads();
    if (wid == 0 && lane < 16) {
        int w = wsum[lane];
#pragma unroll
        for (int o = 1; o < 16; o <<= 1) {
            int t = __shfl_up(w, o);
            if (lane >= o) w += t;
        }
        wsum[lane] = w;
    }
    __syncthreads();
    int excl = (wid ? wsum[wid - 1] : 0) + x - v;
    if (i < N) {
        ptr[i] = excl;
        dinv[i] = rsqrtf((float)v + 1.0f);
    }
    if (tid == 0) bsum[blockIdx.x] = wsum[15];
}

__global__ __launch_bounds__(1024) void scan2_kernel(int* __restrict__ ptr,
                                                     int* __restrict__ cursor,
                                                     const int* __restrict__ bsum,
                                                     int N, int nb) {
    __shared__ int offs;
    const int tid = threadIdx.x;
    if (tid < 64) {
        int s = 0;
        for (int j = (int)tid; j < (int)blockIdx.x; j += 64) s += bsum[j];
#pragma unroll
        for (int o = 1; o < 64; o <<= 1) s += __shfl_xor(s, o);
        if (tid == 0) offs = s;
    }
    __syncthreads();
    int off = offs;
    int i = blockIdx.x * 1024 + tid;
    if (i < N) {
        int v = ptr[i] + off;
        ptr[i] = v;
        cursor[i] = v;
    }
    if ((int)blockIdx.x == nb - 1 && tid == 0) ptr[N] = off + bsum[nb - 1];
}

__global__ void csr_fill_kernel(const int* __restrict__ src, const int* __restrict__ dst,
                                int* __restrict__ cursor, int* __restrict__ csr_src, int E) {
    int e = blockIdx.x * blockDim.x + threadIdx.x;
    if (e < E) {
        int pos = atomicAdd(&cursor[dst[e]], 1);
        csr_src[pos] = src[e];
    }
}

// ---------------- MFMA linear, fp8 permuted out: Yf8 = fp8(dinv[n]*(X@W)) ----------------
template<bool XF32>
__global__ __launch_bounds__(256) void lin_mfma_f8_kernel(const void* __restrict__ Xv,
                                                          const unsigned short* __restrict__ Wt,
                                                          const float* __restrict__ dinv,
                                                          uint2* __restrict__ Yf8, int N) {
    constexpr int NF = 8;
    int wave = threadIdx.x >> 6;
    int lane = threadIdx.x & 63;
    int lr = lane & 15;
    int hk = lane >> 4;
    int rowbase = blockIdx.x * 64 + wave * 16;
    int arow = rowbase + lr; if (arow > N - 1) arow = N - 1;
    float4v acc[NF];
#pragma unroll
    for (int i = 0; i < NF; ++i) acc[i] = (float4v){0.f, 0.f, 0.f, 0.f};
#pragma unroll
    for (int ks = 0; ks < 4; ++ks) {
        int k0 = ks * 32 + hk * 8;
        short8v a;
        if (XF32) {
            const float* xp = (const float*)Xv + (size_t)arow * 128 + k0;
            float4 a0 = *(const float4*)xp;
            float4 a1 = *(const float4*)(xp + 4);
            a[0] = (short)f2bf(a0.x); a[1] = (short)f2bf(a0.y);
            a[2] = (short)f2bf(a0.z); a[3] = (short)f2bf(a0.w);
            a[4] = (short)f2bf(a1.x); a[5] = (short)f2bf(a1.y);
            a[6] = (short)f2bf(a1.z); a[7] = (short)f2bf(a1.w);
        } else {
            a = *(const short8v*)((const unsigned short*)Xv + (size_t)arow * 128 + k0);
        }
#pragma unroll
        for (int nf = 0; nf < NF; ++nf) {
            short8v b = *(const short8v*)(Wt + (size_t)(nf * 16 + lr) * 128 + k0);
            acc[nf] = __builtin_amdgcn_mfma_f32_16x16x32_bf16(a, b, acc[nf], 0, 0, 0);
        }
    }
#pragma unroll
    for (int r = 0; r < 4; ++r) {
        int orow = rowbase + hk * 4 + r;
        if (orow < N) {
            float s = dinv[orow];
            int w0 = __builtin_amdgcn_cvt_pk_fp8_f32(acc[0][r] * s, acc[1][r] * s, 0, 0);
            w0 = __builtin_amdgcn_cvt_pk_fp8_f32(acc[2][r] * s, acc[3][r] * s, w0, 1);
            int w1 = __builtin_amdgcn_cvt_pk_fp8_f32(acc[4][r] * s, acc[5][r] * s, 0, 0);
            w1 = __builtin_amdgcn_cvt_pk_fp8_f32(acc[6][r] * s, acc[7][r] * s, w1, 1);
            Yf8[(size_t)orow * 16 + lr] = make_uint2((unsigned)w0, (unsigned)w1);
        }
    }
}

// ---------------- GAT linear (KO=256) + fused attention logits; fp8 permuted output ----------------
__global__ __launch_bounds__(256) void lin_mfma_attn_kernel(const unsigned short* __restrict__ X,
                                                            const unsigned short* __restrict__ Wt,
                                                            const float* __restrict__ attS,
                                                            const float* __restrict__ attD,
                                                            uint2* __restrict__ Yf8,
                                                            float2* __restrict__ al_s2,
                                                            float2* __restrict__ al_d2, int N) {
    constexpr int NF = 16;
    int wave = threadIdx.x >> 6;
    int lane = threadIdx.x & 63;
    int lr = lane & 15;
    int hk = lane >> 4;
    int rowbase = blockIdx.x * 64 + wave * 16;
    int arow = rowbase + lr; if (arow > N - 1) arow = N - 1;
    float4v acc[NF];
#pragma unroll
    for (int i = 0; i < NF; ++i) acc[i] = (float4v){0.f, 0.f, 0.f, 0.f};
#pragma unroll
    for (int ks = 0; ks < 4; ++ks) {
        int k0 = ks * 32 + hk * 8;
        short8v a = *(const short8v*)(X + (size_t)arow * 128 + k0);
#pragma unroll
        for (int nf = 0; nf < NF; ++nf) {
            short8v b = *(const short8v*)(Wt + (size_t)(nf * 16 + lr) * 128 + k0);
            acc[nf] = __builtin_amdgcn_mfma_f32_16x16x32_bf16(a, b, acc[nf], 0, 0, 0);
        }
    }
    float as0[8], as1[8], ad0[8], ad1[8];
#pragma unroll
    for (int q = 0; q < 8; ++q) {
        as0[q] = attS[q * 16 + lr];
        as1[q] = attS[128 + q * 16 + lr];
        ad0[q] = attD[q * 16 + lr];
        ad1[q] = attD[128 + q * 16 + lr];
    }
#pragma unroll
    for (int r = 0; r < 4; ++r) {
        int orow = rowbase + hk * 4 + r;
        float s0 = 0.f, s1 = 0.f, d0 = 0.f, d1 = 0.f;
#pragma unroll
        for (int q = 0; q < 8; ++q) {
            s0 += acc[q][r] * as0[q];
            d0 += acc[q][r] * ad0[q];
            s1 += acc[q + 8][r] * as1[q];
            d1 += acc[q + 8][r] * ad1[q];
        }
#pragma unroll
        for (int o = 1; o < 16; o <<= 1) {
            s0 += __shfl_xor(s0, o);
            s1 += __shfl_xor(s1, o);
            d0 += __shfl_xor(d0, o);
            d1 += __shfl_xor(d1, o);
        }
        if (orow < N) {
            int w0 = __builtin_amdgcn_cvt_pk_fp8_f32(acc[0][r], acc[1][r], 0, 0);
            w0 = __builtin_amdgcn_cvt_pk_fp8_f32(acc[2][r], acc[3][r], w0, 1);
            int w1 = __builtin_amdgcn_cvt_pk_fp8_f32(acc[4][r], acc[5][r], 0, 0);
            w1 = __builtin_amdgcn_cvt_pk_fp8_f32(acc[6][r], acc[7][r], w1, 1);
            Yf8[(size_t)orow * 32 + lr] = make_uint2((unsigned)w0, (unsigned)w1);
            int w2 = __builtin_amdgcn_cvt_pk_fp8_f32(acc[8][r], acc[9][r], 0, 0);
            w2 = __builtin_amdgcn_cvt_pk_fp8_f32(acc[10][r], acc[11][r], w2, 1);
            int w3 = __builtin_amdgcn_cvt_pk_fp8_f32(acc[12][r], acc[13][r], 0, 0);
            w3 = __builtin_amdgcn_cvt_pk_fp8_f32(acc[14][r], acc[15][r], w3, 1);
            Yf8[(size_t)orow * 32 + 16 + lr] = make_uint2((unsigned)w2, (unsigned)w3);
            if (lr == 0) {
                al_s2[orow] = make_float2(s0, s1);
                al_d2[orow] = make_float2(d0, d1);
            }
        }
    }
}

// ---------------- GCN gather (fp8 rows, dinv pre-folded): out = relu(dn*sum + b), bf16 out ----------------
__global__ __launch_bounds__(256) void gcn_gather_kernel(const uint2* __restrict__ y,
                                                         const float* __restrict__ dinv,
                                                         const int* __restrict__ ptr,
                                                         const int* __restrict__ csr,
                                                         const float* __restrict__ bias,
                                                         uint4* __restrict__ out, int N) {
    __shared__ int stg[4][64];
    __shared__ float vals[4][128];
    int w = threadIdx.x >> 6;
    int node = blockIdx.x * 4 + w;
    if (node >= N) return;
    int lane = threadIdx.x & 63;
    int q = lane & 15;
    int g = lane >> 4;
    float a0 = 0.f, a1 = 0.f, a2 = 0.f, a3 = 0.f, a4 = 0.f, a5 = 0.f, a6 = 0.f, a7 = 0.f;
    int b0 = ptr[node], b1 = ptr[node + 1];
    for (int p0 = b0; p0 < b1; p0 += 64) {
        int m = b1 - p0; if (m > 64) m = 64;
        if (lane < m) stg[w][lane] = __builtin_nontemporal_load(csr + p0 + lane);
        int j = g;
        for (; j + 4 < m; j += 8) {
            int s0 = stg[w][j], s1 = stg[w][j + 4];
            uint2 u0 = y[(size_t)s0 * 16 + q];
            uint2 u1 = y[(size_t)s1 * 16 + q];
            f32x2 p0v = __builtin_amdgcn_cvt_pk_f32_fp8(u0.x, 0);
            f32x2 p1v = __builtin_amdgcn_cvt_pk_f32_fp8(u0.x, 1);
            f32x2 p2v = __builtin_amdgcn_cvt_pk_f32_fp8(u0.y, 0);
            f32x2 p3v = __builtin_amdgcn_cvt_pk_f32_fp8(u0.y, 1);
            f32x2 q0v = __builtin_amdgcn_cvt_pk_f32_fp8(u1.x, 0);
            f32x2 q1v = __builtin_amdgcn_cvt_pk_f32_fp8(u1.x, 1);
            f32x2 q2v = __builtin_amdgcn_cvt_pk_f32_fp8(u1.y, 0);
            f32x2 q3v = __builtin_amdgcn_cvt_pk_f32_fp8(u1.y, 1);
            a0 += p0v[0] + q0v[0]; a1 += p0v[1] + q0v[1];
            a2 += p1v[0] + q1v[0]; a3 += p1v[1] + q1v[1];
            a4 += p2v[0] + q2v[0]; a5 += p2v[1] + q2v[1];
            a6 += p3v[0] + q3v[0]; a7 += p3v[1] + q3v[1];
        }
        if (j < m) {
            int s0 = stg[w][j];
            uint2 u0 = y[(size_t)s0 * 16 + q];
            f32x2 p0v = __builtin_amdgcn_cvt_pk_f32_fp8(u0.x, 0);
            f32x2 p1v = __builtin_amdgcn_cvt_pk_f32_fp8(u0.x, 1);
            f32x2 p2v = __builtin_amdgcn_cvt_pk_f32_fp8(u0.y, 0);
            f32x2 p3v = __builtin_amdgcn_cvt_pk_f32_fp8(u0.y, 1);
            a0 += p0v[0]; a1 += p0v[1];
            a2 += p1v[0]; a3 += p1v[1];
            a4 += p2v[0]; a5 += p2v[1];
            a6 += p3v[0]; a7 += p3v[1];
        }
    }
#pragma unroll
    for (int o = 16; o < 64; o <<= 1) {
        a0 += __shfl_xor(a0, o); a1 += __shfl_xor(a1, o);
        a2 += __shfl_xor(a2, o); a3 += __shfl_xor(a3, o);
        a4 += __shfl_xor(a4, o); a5 += __shfl_xor(a5, o);
        a6 += __shfl_xor(a6, o); a7 += __shfl_xor(a7, o);
    }
    // self loop
    {
        uint2 u = y[(size_t)node * 16 + q];
        f32x2 p0v = __builtin_amdgcn_cvt_pk_f32_fp8(u.x, 0);
        f32x2 p1v = __builtin_amdgcn_cvt_pk_f32_fp8(u.x, 1);
        f32x2 p2v = __builtin_amdgcn_cvt_pk_f32_fp8(u.y, 0);
        f32x2 p3v = __builtin_amdgcn_cvt_pk_f32_fp8(u.y, 1);
        a0 += p0v[0]; a1 += p0v[1];
        a2 += p1v[0]; a3 += p1v[1];
        a4 += p2v[0]; a5 += p2v[1];
        a6 += p3v[0]; a7 += p3v[1];
    }
    // un-permute: lane q's value i is column i*16+q; store at p=q*8+i, read p=(c&15)*8+(c>>4)
    if (lane < 16) {
        float dn = dinv[node];
        vals[w][q * 8 + 0] = a0 * dn; vals[w][q * 8 + 1] = a1 * dn;
        vals[w][q * 8 + 2] = a2 * dn; vals[w][q * 8 + 3] = a3 * dn;
        vals[w][q * 8 + 4] = a4 * dn; vals[w][q * 8 + 5] = a5 * dn;
        vals[w][q * 8 + 6] = a6 * dn; vals[w][q * 8 + 7] = a7 * dn;
    }
    if (lane < 16) {
        float o[8];
#pragma unroll
        for (int i = 0; i < 8; ++i) {
            int c = q * 8 + i;
            int p = (c & 15) * 8 + (c >> 4);
            o[i] = fmaxf(vals[w][p] + bias[c], 0.f);
        }
        out[(size_t)node * 16 + q] = make_uint4(pack2(o[0], o[1]), pack2(o[2], o[3]),
                                                pack2(o[4], o[5]), pack2(o[6], o[7]));
    }
}

// ---------------- GAT gather: fp8 rows (256B), 32 lanes/row, 2 edges in flight ----------------
__global__ __launch_bounds__(256) void gat_gather_kernel(const uint2* __restrict__ h2,
                                                         const float2* __restrict__ al_s2,
                                                         const float2* __restrict__ al_d2,
                                                         const int* __restrict__ ptr,
                                                         const int* __restrict__ csr,
                                                         const float* __restrict__ bias,
                                                         uint4* __restrict__ out, int N) {
    __shared__ uint4 stg[4][64];
    __shared__ float vals[4][128];
    int w = threadIdx.x >> 6;
    int node = blockIdx.x * 4 + w;
    if (node >= N) return;
    int lane = threadIdx.x & 63;
    int li = lane & 31;
    int head = li >> 4;
    int g = lane >> 5;
    int b0 = ptr[node], b1 = ptr[node + 1];
    float2 ad = al_d2[node];

    float den0 = 0.f, den1 = 0.f;
    float a0 = 0.f, a1 = 0.f, a2 = 0.f, a3 = 0.f, a4 = 0.f, a5 = 0.f, a6 = 0.f, a7 = 0.f;

    for (int p0 = b0; p0 < b1; p0 += 64) {
        int m = b1 - p0; if (m > 64) m = 64;
        int idx = (lane < m) ? __builtin_nontemporal_load(csr + p0 + lane) : 0;
        float2 als = al_s2[idx];
        float e0 = __expf(lrelu02(als.x + ad.x));
        float e1 = __expf(lrelu02(als.y + ad.y));
        if (lane >= m) { e0 = 0.f; e1 = 0.f; }
        den0 += e0; den1 += e1;
        stg[w][lane] = make_uint4((unsigned)idx, __float_as_uint(e0), __float_as_uint(e1), 0u);
        int j = g;
        for (; j + 2 < m; j += 4) {
            uint4 t0 = stg[w][j], t1 = stg[w][j + 2];
            uint2 u0 = h2[(size_t)t0.x * 32 + li];
            uint2 u1 = h2[(size_t)t1.x * 32 + li];
            float c0 = __uint_as_float(head ? t0.z : t0.y);
            float c1 = __uint_as_float(head ? t1.z : t1.y);
            f32x2 p0v = __builtin_amdgcn_cvt_pk_f32_fp8(u0.x, 0);
            f32x2 p1v = __builtin_amdgcn_cvt_pk_f32_fp8(u0.x, 1);
            f32x2 p2v = __builtin_amdgcn_cvt_pk_f32_fp8(u0.y, 0);
            f32x2 p3v = __builtin_amdgcn_cvt_pk_f32_fp8(u0.y, 1);
            f32x2 q0v = __builtin_amdgcn_cvt_pk_f32_fp8(u1.x, 0);
            f32x2 q1v = __builtin_amdgcn_cvt_pk_f32_fp8(u1.x, 1);
            f32x2 q2v = __builtin_amdgcn_cvt_pk_f32_fp8(u1.y, 0);
            f32x2 q3v = __builtin_amdgcn_cvt_pk_f32_fp8(u1.y, 1);
            a0 += p0v[0] * c0 + q0v[0] * c1; a1 += p0v[1] * c0 + q0v[1] * c1;
            a2 += p1v[0] * c0 + q1v[0] * c1; a3 += p1v[1] * c0 + q1v[1] * c1;
            a4 += p2v[0] * c0 + q2v[0] * c1; a5 += p2v[1] * c0 + q2v[1] * c1;
            a6 += p3v[0] * c0 + q3v[0] * c1; a7 += p3v[1] * c0 + q3v[1] * c1;
        }
        if (j < m) {
            uint4 t0 = stg[w][j];
            uint2 u0 = h2[(size_t)t0.x * 32 + li];
            float c0 = __uint_as_float(head ? t0.z : t0.y);
            f32x2 p0v = __builtin_amdgcn_cvt_pk_f32_fp8(u0.x, 0);
            f32x2 p1v = __builtin_amdgcn_cvt_pk_f32_fp8(u0.x, 1);
            f32x2 p2v = __builtin_amdgcn_cvt_pk_f32_fp8(u0.y, 0);
            f32x2 p3v = __builtin_amdgcn_cvt_pk_f32_fp8(u0.y, 1);
            a0 += p0v[0] * c0; a1 += p0v[1] * c0;
            a2 += p1v[0] * c0; a3 += p1v[1] * c0;
            a4 += p2v[0] * c0; a5 += p2v[1] * c0;
            a6 += p3v[0] * c0; a7 += p3v[1] * c0;
        }
    }
    a0 += __shfl_xor(a0, 32); a1 += __shfl_xor(a1, 32);
    a2 += __shfl_xor(a2, 32); a3 += __shfl_xor(a3, 32);
    a4 += __shfl_xor(a4, 32); a5 += __shfl_xor(a5, 32);
    a6 += __shfl_xor(a6, 32); a7 += __shfl_xor(a7, 32);
#pragma unroll
    for (int o = 1; o < 64; o <<= 1) {
        den0 += __shfl_xor(den0, o);
        den1 += __shfl_xor(den1, o);
    }
    {
        float2 as_ = al_s2[node];
        float e0s = __expf(lrelu02(as_.x + ad.x));
        float e1s = __expf(lrelu02(as_.y + ad.y));
        den0 += e0s; den1 += e1s;
        float ea = head ? e1s : e0s;
        uint2 u = h2[(size_t)node * 32 + li];
        f32x2 p0v = __builtin_amdgcn_cvt_pk_f32_fp8(u.x, 0);
        f32x2 p1v = __builtin_amdgcn_cvt_pk_f32_fp8(u.x, 1);
        f32x2 p2v = __builtin_amdgcn_cvt_pk_f32_fp8(u.y, 0);
        f32x2 p3v = __builtin_amdgcn_cvt_pk_f32_fp8(u.y, 1);
        a0 += ea * p0v[0]; a1 += ea * p0v[1];
        a2 += ea * p1v[0]; a3 += ea * p1v[1];
        a4 += ea * p2v[0]; a5 += ea * p2v[1];
        a6 += ea * p3v[0]; a7 += ea * p3v[1];
    }
    float inv = 1.f / ((head ? den1 : den0) + 1e-16f);
    a0 *= inv; a1 *= inv; a2 *= inv; a3 *= inv;
    a4 *= inv; a5 *= inv; a6 *= inv; a7 *= inv;
    a0 += __shfl_xor(a0, 16); a1 += __shfl_xor(a1, 16);
    a2 += __shfl_xor(a2, 16); a3 += __shfl_xor(a3, 16);
    a4 += __shfl_xor(a4, 16); a5 += __shfl_xor(a5, 16);
    a6 += __shfl_xor(a6, 16); a7 += __shfl_xor(a7, 16);
    if (lane < 16) {
        vals[w][lane * 8 + 0] = a0; vals[w][lane * 8 + 1] = a1;
        vals[w][lane * 8 + 2] = a2; vals[w][lane * 8 + 3] = a3;
        vals[w][lane * 8 + 4] = a4; vals[w][lane * 8 + 5] = a5;
        vals[w][lane * 8 + 6] = a6; vals[w][lane * 8 + 7] = a7;
    }
    if (lane < 16) {
        float o[8];
#pragma unroll
        for (int i = 0; i < 8; ++i) {
            int c = lane * 8 + i;
            int p = (c & 15) * 8 + (c >> 4);
            o[i] = fmaxf(0.5f * vals[w][p] + bias[c], 0.f);
        }
        out[(size_t)node * 16 + lane] = make_uint4(pack2(o[0], o[1]), pack2(o[2], o[3]),
                                                   pack2(o[4], o[5]), pack2(o[6], o[7]));
    }
}

// ---------------- pooling (bf16 input, sorted batch): one 32-node chunk per wave ----------------
__global__ __launch_bounds__(256) void pool_kernel(const unsigned* __restrict__ h,
                                                   const int* __restrict__ batch,
                                                   float* __restrict__ sums,
                                                   float* __restrict__ counts, int N) {
    const int PER = 32;
    int wave = threadIdx.x >> 6;
    int f = threadIdx.x & 63;
    int n0 = (blockIdx.x * 4 + wave) * PER;
    int n1 = min(N, n0 + PER);
    if (n0 >= n1) return;
    int cur = -1;
    float a0 = 0.f, a1 = 0.f, cnt = 0.f;
    for (int n = n0; n < n1; ++n) {
        int g = batch[n];
        if (g != cur) {
            if (cur >= 0) {
                atomicAdd(&sums[cur * 128 + f * 2], a0);
                atomicAdd(&sums[cur * 128 + f * 2 + 1], a1);
                if (f == 0) atomicAdd(&counts[cur], cnt);
            }
            cur = g; a0 = a1 = cnt = 0.f;
        }
        unsigned u = h[(size_t)n * 64 + f];
        a0 += bflo(u); a1 += bfhi(u); cnt += 1.f;
    }
    if (cur >= 0) {
        atomicAdd(&sums[cur * 128 + f * 2], a0);
        atomicAdd(&sums[cur * 128 + f * 2 + 1], a1);
        if (f == 0) atomicAdd(&counts[cur], cnt);
    }
}

// ---------------- MLP head + log_softmax: one block per graph ----------------
__global__ __launch_bounds__(128) void head_kernel(const float* __restrict__ sums,
                                                   const float* __restrict__ counts,
                                                   const float* __restrict__ fc1W,
                                                   const float* __restrict__ fc1b,
                                                   const float* __restrict__ fc2W,
                                                   const float* __restrict__ fc2b,
                                                   float* __restrict__ out) {
    int g = blockIdx.x;
    int tid = threadIdx.x;
    __shared__ float gm[128];
    __shared__ float h1[128];
    __shared__ float part[4][32];
    float s = sums[g * 128 + tid];
    gm[tid] = s / fmaxf(counts[g], 1.f) + s;
    __syncthreads();
    float acc = fc1b[tid];
    for (int k = 0; k < 128; ++k) acc += gm[k] * fc1W[k * 128 + tid];
    h1[tid] = fmaxf(acc, 0.f);
    __syncthreads();
    int c = tid & 31, p = tid >> 5;
    float a2 = 0.f;
    for (int k = p * 32; k < p * 32 + 32; ++k) a2 += h1[k] * fc2W[k * 32 + c];
    part[p][c] = a2;
    __syncthreads();
    if (tid < 32) {
        float v = part[0][tid] + part[1][tid] + part[2][tid] + part[3][tid] + fc2b[tid];
        float m = v;
#pragma unroll
        for (int o = 1; o < 32; o <<= 1) m = fmaxf(m, __shfl_xor(m, o));
        float e = __expf(v - m);
        float ssum = e;
#pragma unroll
        for (int o = 1; o < 32; o <<= 1) ssum += __shfl_xor(ssum, o);
        out[g * 32 + tid] = v - m - logf(ssum);
    }
}

// ---------------- launch ----------------

extern "C" void kernel_launch(void* const* d_in, const int* in_sizes, int n_in,
                              void* d_out, int out_size, void* d_ws, size_t ws_size,
                              hipStream_t stream) {
    const float* x     = (const float*)d_in[0];
    const int*   eidx  = (const int*)d_in[1];
    const int*   batch = (const int*)d_in[2];
    const float* W1 = (const float*)d_in[3];
    const float* b1 = (const float*)d_in[4];
    const float* W2 = (const float*)d_in[5];
    const float* b2 = (const float*)d_in[6];
    const float* W3 = (const float*)d_in[7];
    const float* b3 = (const float*)d_in[8];
    const float* gatW   = (const float*)d_in[9];
    const float* attSrc = (const float*)d_in[10];
    const float* attDst = (const float*)d_in[11];
    const float* gatB   = (const float*)d_in[12];
    const float* fc1W = (const float*)d_in[13];
    const float* fc1b = (const float*)d_in[14];
    const float* fc2W = (const float*)d_in[15];
    const float* fc2b = (const float*)d_in[16];
    float* out = (float*)d_out;

    const int N  = in_sizes[0] / 128;
    const int E  = in_sizes[1] / 2;
    const int OUT = in_sizes[15] / 128;
    const int G   = out_size / OUT;

    const int* src = eidx;
    const int* dst = eidx + E;

    // workspace carve-up
    char* ws = (char*)d_ws;
    size_t off = 0;
    auto carve = [&](size_t bytes) { char* p = ws + off; off += (bytes + 255) & ~255ull; return p; };
    uint2*          yf8  = (uint2*)carve((size_t)N * 128);            // fp8 lin output (permuted)
    unsigned short* hb   = (unsigned short*)carve((size_t)N * 128 * 2); // bf16 gather output
    uint2*          gb8  = (uint2*)carve((size_t)N * 256);            // fp8 GAT lin output
    unsigned short* ob   = (unsigned short*)carve((size_t)N * 128 * 2); // bf16 GAT output (pool input)
    unsigned short* Wt1 = (unsigned short*)carve(128 * 128 * 2);
    unsigned short* Wt2 = (unsigned short*)carve(128 * 128 * 2);
    unsigned short* Wt3 = (unsigned short*)carve(128 * 128 * 2);
    unsigned short* WtG = (unsigned short*)carve(256 * 128 * 2);
    int*   deg   = (int*)carve((size_t)N * 4);
    float* dinv  = (float*)carve((size_t)N * 4);
    int*   ptr   = (int*)carve((size_t)(N + 1) * 4);
    int*   cursor= (int*)carve((size_t)N * 4);
    int*   csrS  = (int*)carve((size_t)E * 4);
    int*   bsum  = (int*)carve(256 * 4);
    float* al_s  = (float*)carve((size_t)N * 2 * 4);
    float* al_d  = (float*)carve((size_t)N * 2 * 4);
    float* sums  = (float*)carve((size_t)G * 128 * 4);
    float* cnts  = (float*)carve((size_t)G * 4);

    const int B = 256;
    dim3 blk(B);
    auto cdiv = [](long long a, long long b) { return (int)((a + b - 1) / b); };
    const int nb = cdiv(N, 1024);

    // setup: weight conversions + zero deg/sums/cnts (single launch)
    setup_kernel<<<cdiv(81920 + N + G * 128 + G, B), blk, 0, stream>>>(
        W1, W2, W3, gatW, Wt1, Wt2, Wt3, WtG, deg, sums, cnts, N, G);

    // CSR build over dst (parallel two-phase scan)
    deg_kernel<<<cdiv(E, B), blk, 0, stream>>>(dst, deg, E);
    scan1_kernel<<<nb, 1024, 0, stream>>>(deg, ptr, dinv, bsum, N);
    scan2_kernel<<<nb, 1024, 0, stream>>>(ptr, cursor, bsum, N, nb);
    csr_fill_kernel<<<cdiv(E, B), blk, 0, stream>>>(src, dst, cursor, csrS, E);

    // GCN layers (fp8 lin outputs pre-scaled by dinv, bf16 gather outputs)
    lin_mfma_f8_kernel<true><<<cdiv(N, 64), blk, 0, stream>>>(x, Wt1, dinv, yf8, N);
    gcn_gather_kernel<<<cdiv(N, 4), blk, 0, stream>>>(yf8, dinv, ptr, csrS, b1, (uint4*)hb, N);
    lin_mfma_f8_kernel<false><<<cdiv(N, 64), blk, 0, stream>>>(hb, Wt2, dinv, yf8, N);
    gcn_gather_kernel<<<cdiv(N, 4), blk, 0, stream>>>(yf8, dinv, ptr, csrS, b2, (uint4*)hb, N);
    lin_mfma_f8_kernel<false><<<cdiv(N, 64), blk, 0, stream>>>(hb, Wt3, dinv, yf8, N);
    gcn_gather_kernel<<<cdiv(N, 4), blk, 0, stream>>>(yf8, dinv, ptr, csrS, b3, (uint4*)hb, N);

    // GAT: GEMM + fused attention logits (fp8 out), then gather
    lin_mfma_attn_kernel<<<cdiv(N, 64), blk, 0, stream>>>(hb, WtG, attSrc, attDst, gb8,
                                                          (float2*)al_s, (float2*)al_d, N);
    gat_gather_kernel<<<cdiv(N, 4), blk, 0, stream>>>(gb8, (const float2*)al_s, (const float2*)al_d,
                                                      ptr, csrS, gatB, (uint4*)ob, N);

    // pooling
    pool_kernel<<<cdiv(N, 128), blk, 0, stream>>>((const unsigned*)ob, batch, sums, cnts, N);

    // head: one block per graph
    head_kernel<<<G, dim3(128), 0, stream>>>(sums, cnts, fc1W, fc1b, fc2W, fc2b, out);
}